// Round 1
// baseline (4060.350 us; speedup 1.0000x reference)
//
#include <hip/hip_runtime.h>

// ---------------------------------------------------------------------------
// VanillaCRF forward on MI355X.
// Structure: per-timestep kernels (graph nodes), bf16 MFMA 16x16x32.
// "k-packed" layout for all MFMA operands: elem(row r, col k) at
//   base[((k>>3)*R + r)*8 + (k&7)]   (R = #rows), so A/B frags are direct
// coalesced 16B-per-lane global (or LDS) loads.
// Frag layouts (m89/m91-verified): A[m=lane&15][k=(lane>>4)*8+j],
// B[k=(lane>>4)*8+j][n=lane&15], D[row=(lane>>4)*4+reg][col=lane&15].
// ---------------------------------------------------------------------------

typedef short v8s __attribute__((ext_vector_type(8)));
typedef float v4f __attribute__((ext_vector_type(4)));
typedef unsigned short u16;

#define MFMA(a, b, c) __builtin_amdgcn_mfma_f32_16x16x32_bf16((a), (b), (c), 0, 0, 0)

static constexpr size_t WMAT    = (size_t)96 * 3072 * 8;   // u16 elems per 3072x768 kp matrix
static constexpr size_t SLOT64  = (size_t)96 * 64 * 8;     // u16 elems per 64-row, 768-col kp slot
static constexpr size_t SLOT16  = (size_t)96 * 16 * 8;
static constexpr size_t SLOT128 = (size_t)96 * 128 * 8;

static constexpr size_t OFF_CALL = 0;
static constexpr size_t SZ_CALL  = (size_t)8 * 64 * 768 * 4;
static constexpr size_t OFF_EM   = OFF_CALL + SZ_CALL;
static constexpr size_t SZ_EM    = (size_t)2 * 64 * 128 * 2 * 4;
static constexpr size_t OFF_XW0  = OFF_EM + SZ_EM;
static constexpr size_t SZ_XW    = (size_t)4 * 128 * 3072 * 4;
static constexpr size_t OFF_XW1  = OFF_XW0 + SZ_XW;
static constexpr size_t OFF_SEQ  = OFF_XW1 + SZ_XW;
static constexpr size_t SZ_SEQ   = (size_t)96 * 128 * 8 * 2;
static constexpr size_t OFF_LABS = OFF_SEQ + SZ_SEQ;
static constexpr size_t SZ_LABS  = 512;
static constexpr size_t OFF_W0   = OFF_LABS + SZ_LABS;
static constexpr size_t SZ_W4    = (size_t)4 * WMAT * 2;
static constexpr size_t OFF_W1X  = OFF_W0 + SZ_W4;
static constexpr size_t OFF_W1R  = OFF_W1X + SZ_W4;
static constexpr size_t OFF_F0   = OFF_W1R + SZ_W4;
static constexpr size_t SZ_F0    = (size_t)2 * 129 * SLOT16 * 2;
static constexpr size_t OFF_H0F  = OFF_F0 + SZ_F0;
static constexpr size_t SZ_H0F   = (size_t)2 * SLOT128 * 2;
static constexpr size_t OFF_B0   = OFF_H0F + SZ_H0F;
static constexpr size_t SZ_S64   = (size_t)2 * 129 * SLOT64 * 2;
static constexpr size_t OFF_F1   = OFF_B0 + SZ_S64;
static constexpr size_t OFF_B1   = OFF_F1 + SZ_S64;
static constexpr size_t WS_NEED  = OFF_B1 + SZ_S64;   // ~154 MB

static __device__ __forceinline__ u16 f2b(float f) {
  unsigned int u = __float_as_uint(f);
  unsigned int r = (u + 0x7FFFu + ((u >> 16) & 1u)) >> 16;   // RNE
  return (u16)r;
}
static __device__ __forceinline__ float b2f(u16 u) {
  return __uint_as_float(((unsigned int)u) << 16);
}
static __device__ __forceinline__ float sigf(float x) {
  return 1.0f / (1.0f + __expf(-x));
}
static __device__ __forceinline__ float tanhfast(float x) {
  return 1.0f - 2.0f / (__expf(2.0f * x) + 1.0f);
}
static __device__ __forceinline__ float lse2(float a, float b) {
  float mx = fmaxf(a, b);
  return mx + __logf(__expf(a - mx) + __expf(b - mx));
}

// stage 48 kblks of a [96][3072][8]-kp weight matrix, rows = 4 gate blocks of
// 16 units starting at jb, into lds[48][64][8]
static __device__ __forceinline__ void stage_w(const u16* mat, int kb0, int jb, u16* lds) {
  const int4* src = (const int4*)mat;
  int4* dst = (int4*)lds;
  int tid = threadIdx.x;
#pragma unroll
  for (int it = 0; it < 12; ++it) {
    int ck = it * 256 + tid;          // 0..3071
    int kb = ck >> 6;
    int r = ck & 63;
    int g = (r >> 4) * 768 + jb + (r & 15);
    dst[ck] = src[(size_t)(kb0 + kb) * 3072 + g];
  }
}

// ---------------------------------------------------------------------------
__global__ void init_zero(float* c_all, u16* f0a, u16* f0b, u16* b0a, u16* b0b,
                          u16* f1a, u16* f1b, u16* b1a, u16* b1b) {
  int idx = blockIdx.x * 256 + threadIdx.x;   // grid 1536*256 = 393216
  c_all[idx] = 0.0f;
  if (idx < (int)SLOT16) { f0a[idx] = 0; f0b[idx] = 0; }
  if (idx < (int)SLOT64) {
    b0a[idx] = 0; b0b[idx] = 0;
    f1a[idx] = 0; f1b[idx] = 0;
    b1a[idx] = 0; b1b[idx] = 0;
  }
}

__global__ void build_seq(const float* user, const float* sysr, const int* ulab,
                          const int* slab, u16* seqkp, int* labs) {
  int idx = blockIdx.x * 256 + threadIdx.x;   // grid 384*256 = 98304
  int t = idx / 768;
  int hh = idx - t * 768;
  float v = (t & 1) ? sysr[(t >> 1) * 768 + hh] : user[(t >> 1) * 768 + hh];
  seqkp[((size_t)(hh >> 3) * 128 + t) * 8 + (hh & 7)] = f2b(v);
  if (idx < 128) labs[idx] = (idx & 1) ? slab[idx >> 1] : ulab[idx >> 1];
}

// 12 matrices -> kp bf16: grp0 Whh0, grp1 Wih1[:,768:], grp2 Whh1
__global__ void cvt_w(const float* postWhh0, const float* priWhh0,
                      const float* postWih1, const float* priWih1,
                      const float* postWhh1, const float* priWhh1,
                      u16* W0kp, u16* W1xkp, u16* W1rkp) {
  int mat = blockIdx.y;
  int grp = mat >> 2;
  int sub = mat & 3;
  int m = sub >> 1;
  int dirw = sub & 1;
  const float* src;
  int stride, coff;
  u16* dstb;
  if (grp == 0)      { src = m ? priWhh0 : postWhh0; stride = 768;  coff = 0;   dstb = W0kp; }
  else if (grp == 1) { src = m ? priWih1 : postWih1; stride = 1536; coff = 768; dstb = W1xkp; }
  else               { src = m ? priWhh1 : postWhh1; stride = 768;  coff = 0;   dstb = W1rkp; }
  src += (size_t)dirw * 3072 * stride;
  int cid = blockIdx.x * 256 + threadIdx.x;   // grid.x = 1152 -> 294912 = 3072*96
  int g = cid / 96;
  int kb = cid - g * 96;
  const float* s = src + (size_t)g * stride + coff + (size_t)kb * 8;
  union { u16 h[8]; int4 v; } u;
#pragma unroll
  for (int j = 0; j < 8; ++j) u.h[j] = f2b(s[j]);
  ((int4*)(dstb + (size_t)sub * WMAT))[(size_t)kb * 3072 + g] = u.v;
}

// out[md][t][g] = A(128xK) @ W[dir](Kx3072 rows-as-gates) + b ; K=768
__global__ void __launch_bounds__(256) xw_gemm(const u16* Akp, unsigned long long Astride,
                                               const float* Wm0, const float* Wm1, int wstride,
                                               const float* bm0, const float* bm1, float* out) {
  __shared__ u16 lds[48 * 64 * 8];
  int tid = threadIdx.x;
  int lane = tid & 63;
  int wave = tid >> 6;
  int md = blockIdx.y;
  int m = md >> 1;
  int dir = md & 1;
  const u16* A = Akp + (size_t)m * Astride;
  const float* W = (m ? Wm1 : Wm0) + (size_t)dir * 3072 * wstride;
  const float* b = (m ? bm1 : bm0) + dir * 3072;
  int g0 = blockIdx.x * 64;
  int quad = lane >> 4, l15 = lane & 15;
  v4f acc[2][4];
#pragma unroll
  for (int a = 0; a < 2; ++a)
#pragma unroll
    for (int nt = 0; nt < 4; ++nt) acc[a][nt] = (v4f){0.f, 0.f, 0.f, 0.f};

  for (int hfl = 0; hfl < 2; ++hfl) {
    if (hfl) __syncthreads();
    for (int it = 0; it < 12; ++it) {
      int ck = it * 256 + tid;
      int kb = ck >> 6;
      int r = ck & 63;
      int g = g0 + r;
      const float* s = W + (size_t)g * wstride + (size_t)(hfl * 48 + kb) * 8;
      union { u16 h[8]; int4 v; } u;
#pragma unroll
      for (int j = 0; j < 8; ++j) u.h[j] = f2b(s[j]);
      *(int4*)(lds + (size_t)ck * 8) = u.v;
    }
    __syncthreads();
    for (int lt = 0; lt < 12; ++lt) {
      int kblk = (hfl * 12 + lt) * 4 + quad;
      v8s a0 = ((const v8s*)A)[(size_t)kblk * 128 + (wave * 2 + 0) * 16 + l15];
      v8s a1 = ((const v8s*)A)[(size_t)kblk * 128 + (wave * 2 + 1) * 16 + l15];
#pragma unroll
      for (int nt = 0; nt < 4; ++nt) {
        v8s bb = *(const v8s*)(lds + ((size_t)((lt * 4 + quad) * 64) + nt * 16 + l15) * 8);
        acc[0][nt] = MFMA(a0, bb, acc[0][nt]);
        acc[1][nt] = MFMA(a1, bb, acc[1][nt]);
      }
    }
  }
#pragma unroll
  for (int a = 0; a < 2; ++a)
#pragma unroll
    for (int nt = 0; nt < 4; ++nt) {
      int g = g0 + nt * 16 + l15;
      float bv = b[g];
#pragma unroll
      for (int r = 0; r < 4; ++r) {
        int trow = (wave * 2 + a) * 16 + quad * 4 + r;
        out[(size_t)(md * 128 + trow) * 3072 + g] = acc[a][nt][r] + bv;
      }
    }
}

// Phase A: blockIdx.y: 0 post-bwd0, 1 prior-bwd0, 2 post-fwd0, 3 prior-fwd0
__global__ void __launch_bounds__(256) stepA_k(int t, const u16* W0kp, const float* xw0,
                                               u16* B0, u16* F0, u16* h0f, float* c_all) {
  __shared__ u16 lds[48 * 64 * 8];
  int tid = threadIdx.x;
  int lane = tid & 63;
  int wave = tid >> 6;
  int c = blockIdx.y;
  int isf = c >> 1;
  int m = c & 1;
  int dir = isf ? 0 : 1;
  int jb = blockIdx.x * 16;
  int quad = lane >> 4, l15 = lane & 15;
  const u16* mat = W0kp + (size_t)(m * 2 + dir) * WMAT;
  const u16* Asrc;
  int R, rowbase;
  if (isf) { Asrc = F0 + (size_t)(m * 129 + t) * SLOT16; R = 16; rowbase = 0; }
  else     { Asrc = B0 + (size_t)(m * 129 + t + 1) * SLOT64; R = 64; rowbase = wave * 16; }
  v4f acc[4];
#pragma unroll
  for (int gt = 0; gt < 4; ++gt) acc[gt] = (v4f){0.f, 0.f, 0.f, 0.f};
  bool docomp = (!isf) || (wave == 0);

  for (int hfl = 0; hfl < 2; ++hfl) {
    if (hfl) __syncthreads();
    stage_w(mat, hfl * 48, jb, lds);
    __syncthreads();
    if (docomp) {
      for (int lt = 0; lt < 12; ++lt) {
        int kblk = hfl * 48 + lt * 4 + quad;
        v8s a = ((const v8s*)Asrc)[(size_t)kblk * R + rowbase + l15];
#pragma unroll
        for (int gt = 0; gt < 4; ++gt) {
          v8s bb = *(const v8s*)(lds + ((size_t)((lt * 4 + quad) * 4 + gt) * 16 + l15) * 8);
          acc[gt] = MFMA(a, bb, acc[gt]);
        }
      }
    }
  }
  if (!docomp) return;

  int j = jb + l15;
  const float* xw = xw0 + (size_t)((m * 2 + dir) * 128 + t) * 3072;
  float xi = xw[j], xf = xw[768 + j], xg = xw[1536 + j], xo = xw[2304 + j];
  float* cs = c_all + (size_t)c * 64 * 768;
  if (!isf) {
    u16* dst = B0 + (size_t)(m * 129 + t) * SLOT64;
#pragma unroll
    for (int r = 0; r < 4; ++r) {
      int p = wave * 16 + quad * 4 + r;
      float gi = sigf(acc[0][r] + xi), gf = sigf(acc[1][r] + xf);
      float gg = tanhfast(acc[2][r] + xg), go = sigf(acc[3][r] + xo);
      float cold = cs[(size_t)p * 768 + j];
      float cn = gf * cold + gi * gg;
      float hn = go * tanhfast(cn);
      int lenp = 2 * p + 2 - m;
      bool act = t < lenp;
      float ce = act ? cn : 0.f;
      float he = act ? hn : 0.f;
      cs[(size_t)p * 768 + j] = ce;
      dst[((size_t)(j >> 3) * 64 + p) * 8 + (j & 7)] = f2b(he);
    }
  } else {
    if (quad == 0) {  // row p==0 lives in reg 0 of quad 0
      float gi = sigf(acc[0][0] + xi), gf = sigf(acc[1][0] + xf);
      float gg = tanhfast(acc[2][0] + xg), go = sigf(acc[3][0] + xo);
      float cold = cs[j];
      float cn = gf * cold + gi * gg;
      float hn = go * tanhfast(cn);
      cs[j] = cn;
      F0[(size_t)(m * 129 + t + 1) * SLOT16 + ((size_t)(j >> 3) * 16) * 8 + (j & 7)] = f2b(hn);
      h0f[(size_t)m * SLOT128 + ((size_t)(j >> 3) * 128 + t) * 8 + (j & 7)] = f2b(hn);
    }
  }
}

// Phase B: blockIdx.y = m*2+dir (dir 0 = fwd1, 1 = bwd1)
__global__ void __launch_bounds__(256) stepB_k(int t, const u16* W1x, const u16* W1r,
                                               const float* xw1s, const u16* B0, u16* F1,
                                               u16* B1, float* c_all) {
  __shared__ u16 lds[48 * 64 * 8];
  int tid = threadIdx.x;
  int lane = tid & 63;
  int wave = tid >> 6;
  int md = blockIdx.y;
  int m = md >> 1;
  int dir = md & 1;
  int jb = blockIdx.x * 16;
  int quad = lane >> 4, l15 = lane & 15;
  const u16* A1 = B0 + (size_t)(m * 129 + t) * SLOT64;
  const u16* A2 = dir ? (const u16*)(B1 + (size_t)(m * 129 + t + 1) * SLOT64)
                      : (const u16*)(F1 + (size_t)(m * 129 + t) * SLOT64);
  v4f acc[4];
#pragma unroll
  for (int gt = 0; gt < 4; ++gt) acc[gt] = (v4f){0.f, 0.f, 0.f, 0.f};

  for (int q = 0; q < 4; ++q) {
    if (q) __syncthreads();
    const u16* mat = (q < 2 ? W1x : W1r) + (size_t)md * WMAT;
    stage_w(mat, (q & 1) * 48, jb, lds);
    __syncthreads();
    const u16* As = (q < 2) ? A1 : A2;
    int akb0 = (q & 1) * 48;
    for (int lt = 0; lt < 12; ++lt) {
      v8s a = ((const v8s*)As)[(size_t)(akb0 + lt * 4 + quad) * 64 + wave * 16 + l15];
#pragma unroll
      for (int gt = 0; gt < 4; ++gt) {
        v8s bb = *(const v8s*)(lds + ((size_t)((lt * 4 + quad) * 4 + gt) * 16 + l15) * 8);
        acc[gt] = MFMA(a, bb, acc[gt]);
      }
    }
  }

  int j = jb + l15;
  const float* xw = xw1s + (size_t)(md * 128 + t) * 3072;
  float xi = xw[j], xf = xw[768 + j], xg = xw[1536 + j], xo = xw[2304 + j];
  float* cs = c_all + (size_t)(4 + md) * 64 * 768;
  u16* dst = dir ? (B1 + (size_t)(m * 129 + t) * SLOT64)
                 : (F1 + (size_t)(m * 129 + t + 1) * SLOT64);
  const u16* F1t = F1 + (size_t)(m * 129 + t) * SLOT64;
#pragma unroll
  for (int r = 0; r < 4; ++r) {
    int p = wave * 16 + quad * 4 + r;
    float gi = sigf(acc[0][r] + xi), gf = sigf(acc[1][r] + xf);
    float gg = tanhfast(acc[2][r] + xg), go = sigf(acc[3][r] + xo);
    float cold = cs[(size_t)p * 768 + j];
    float cn = gf * cold + gi * gg;
    float hn = go * tanhfast(cn);
    int lenp = 2 * p + 2 - m;
    bool act = t < lenp;
    float he, ce;
    if (!dir) {
      if (act) { he = hn; ce = cn; }
      else { he = b2f(F1t[((size_t)(j >> 3) * 64 + p) * 8 + (j & 7)]); ce = cold; }
    } else {
      he = act ? hn : 0.f;
      ce = act ? cn : 0.f;
    }
    cs[(size_t)p * 768 + j] = ce;
    dst[((size_t)(j >> 3) * 64 + p) * 8 + (j & 7)] = f2b(he);
  }
}

__global__ void __launch_bounds__(256) em_k(const u16* F1, const u16* B1,
                                            const float* pW0, const float* pb0,
                                            const float* pW1, const float* pb1, float* em) {
  int wid = blockIdx.x * 4 + (threadIdx.x >> 6);   // grid 4096 -> 16384 waves
  int lane = threadIdx.x & 63;
  int m = wid >> 13;
  int rem = wid & 8191;
  int p = rem >> 7;
  int t = rem & 127;
  const u16* hf = F1 + (size_t)(m * 129 + t + 1) * SLOT64;
  const u16* hb = B1 + (size_t)(m * 129 + t) * SLOT64;
  const float* Pw = m ? pW1 : pW0;
  const float* Pb = m ? pb1 : pb0;
  float s0 = 0.f, s1 = 0.f;
#pragma unroll
  for (int i = 0; i < 12; ++i) {
    int j = i * 64 + lane;
    size_t o = ((size_t)(j >> 3) * 64 + p) * 8 + (j & 7);
    float vf = b2f(hf[o]);
    float vb = b2f(hb[o]);
    s0 += Pw[j] * vf + Pw[768 + j] * vb;
    s1 += Pw[1536 + j] * vf + Pw[2304 + j] * vb;
  }
  for (int off = 32; off; off >>= 1) {
    s0 += __shfl_down(s0, off, 64);
    s1 += __shfl_down(s1, off, 64);
  }
  if (lane == 0) {
    em[((size_t)(m * 64 + p) * 128 + t) * 2 + 0] = s0 + Pb[0];
    em[((size_t)(m * 64 + p) * 128 + t) * 2 + 1] = s1 + Pb[1];
  }
}

__global__ void final_k(const float* em, const int* labs, const float* T, float* out) {
  int p = threadIdx.x;   // 64 threads, 1 wave
  const float* emP = em + (size_t)p * 128 * 2;
  int lp = 2 * p + 2;
  float T00 = T[0], T01 = T[1], T10 = T[2], T11 = T[3];
  int prevlab = labs[0];
  float gold = emP[prevlab];
  for (int t = 1; t < lp; ++t) {
    int lb = labs[t];
    gold += emP[t * 2 + lb] + (prevlab ? (lb ? T11 : T10) : (lb ? T01 : T00));
    prevlab = lb;
  }
  float a0 = emP[0], a1 = emP[1];
  for (int t = 1; t < lp; ++t) {
    float n0 = lse2(a0 + T00, a1 + T10) + emP[t * 2];
    float n1 = lse2(a0 + T01, a1 + T11) + emP[t * 2 + 1];
    a0 = n0;
    a1 = n1;
  }
  float crf = lse2(a0, a1) - gold;
  const float* emR = em + (size_t)(64 + p) * 128 * 2;
  int lpr = 2 * p + 1;
  float d0 = emR[(lpr - 1) * 2 + 0] - emP[(lp - 1) * 2 + 0];
  float d1 = emR[(lpr - 1) * 2 + 1] - emP[(lp - 1) * 2 + 1];
  float mse = d0 * d0 + d1 * d1;
  for (int off = 32; off; off >>= 1) {
    crf += __shfl_down(crf, off, 64);
    mse += __shfl_down(mse, off, 64);
  }
  if (p == 0) {
    float lc = crf / 64.f;
    float lm = mse / 128.f;
    out[0] = lc;
    out[1] = lm;
    out[2] = lc + 0.1f * lm;
  }
}

// ---------------------------------------------------------------------------
extern "C" void kernel_launch(void* const* d_in, const int* in_sizes, int n_in,
                              void* d_out, int out_size, void* d_ws, size_t ws_size,
                              hipStream_t stream) {
  (void)in_sizes; (void)n_in; (void)out_size;
  if (ws_size < WS_NEED) return;   // diagnosable: output stays poisoned

  const float* user     = (const float*)d_in[0];
  const float* sysr     = (const float*)d_in[1];
  const float* postWih0 = (const float*)d_in[2];
  const float* postWhh0 = (const float*)d_in[3];
  const float* postb0   = (const float*)d_in[4];
  const float* postWih1 = (const float*)d_in[5];
  const float* postWhh1 = (const float*)d_in[6];
  const float* postb1   = (const float*)d_in[7];
  const float* priWih0  = (const float*)d_in[8];
  const float* priWhh0  = (const float*)d_in[9];
  const float* prib0    = (const float*)d_in[10];
  const float* priWih1  = (const float*)d_in[11];
  const float* priWhh1  = (const float*)d_in[12];
  const float* prib1    = (const float*)d_in[13];
  const float* postPW   = (const float*)d_in[14];
  const float* postPb   = (const float*)d_in[15];
  const float* priPW    = (const float*)d_in[16];
  const float* priPb    = (const float*)d_in[17];
  const float* trans    = (const float*)d_in[18];
  const int*   ulab     = (const int*)d_in[19];
  const int*   slab     = (const int*)d_in[20];
  float* out = (float*)d_out;

  char* w = (char*)d_ws;
  float* c_all = (float*)(w + OFF_CALL);
  float* em    = (float*)(w + OFF_EM);
  float* xw0   = (float*)(w + OFF_XW0);
  float* xw1s  = (float*)(w + OFF_XW1);
  u16* seqkp   = (u16*)(w + OFF_SEQ);
  int* labs    = (int*)(w + OFF_LABS);
  u16* W0kp    = (u16*)(w + OFF_W0);
  u16* W1xkp   = (u16*)(w + OFF_W1X);
  u16* W1rkp   = (u16*)(w + OFF_W1R);
  u16* F0      = (u16*)(w + OFF_F0);
  u16* h0f     = (u16*)(w + OFF_H0F);
  u16* B0      = (u16*)(w + OFF_B0);
  u16* F1      = (u16*)(w + OFF_F1);
  u16* B1      = (u16*)(w + OFF_B1);

  init_zero<<<1536, 256, 0, stream>>>(
      c_all,
      F0, F0 + (size_t)129 * SLOT16,
      B0 + (size_t)128 * SLOT64, B0 + (size_t)(129 + 128) * SLOT64,
      F1, F1 + (size_t)129 * SLOT64,
      B1 + (size_t)128 * SLOT64, B1 + (size_t)(129 + 128) * SLOT64);

  build_seq<<<384, 256, 0, stream>>>(user, sysr, ulab, slab, seqkp, labs);

  cvt_w<<<dim3(1152, 12), 256, 0, stream>>>(postWhh0, priWhh0, postWih1, priWih1,
                                            postWhh1, priWhh1, W0kp, W1xkp, W1rkp);

  xw_gemm<<<dim3(48, 4), 256, 0, stream>>>(seqkp, 0ULL, postWih0, priWih0, 768,
                                           postb0, prib0, xw0);

  for (int t = 0; t < 128; ++t)
    stepA_k<<<dim3(48, 4), 256, 0, stream>>>(t, W0kp, xw0, B0, F0, h0f, c_all);

  xw_gemm<<<dim3(48, 4), 256, 0, stream>>>(h0f, (unsigned long long)SLOT128,
                                           postWih1, priWih1, 1536, postb1, prib1, xw1s);

  for (int t = 0; t < 128; ++t)
    stepB_k<<<dim3(48, 4), 256, 0, stream>>>(t, W1xkp, W1rkp, xw1s, B0, F1, B1, c_all);

  em_k<<<4096, 256, 0, stream>>>(F1, B1, postPW, postPb, priPW, priPb, em);

  final_k<<<1, 64, 0, stream>>>(em, labs, trans, out);
}